// Round 5
// baseline (132.205 us; speedup 1.0000x reference)
//
#include <hip/hip_runtime.h>

// AdditiveAttention: b=4, n_q=64, s=1024, Q_DIM=K_DIM=HID=VDIM=512, f32 in/out.
// R5: softmax kernel eliminated — scores emits unnormalized e=exp2(-2log2e*t)
//     (safe: |t|<=12 so no overflow; max-subtract unnecessary) + atomic row
//     sums; reduce kernel divides. 5 kernels total.

static constexpr int SLEN = 1024;
static constexpr int DIM  = 512;
static constexpr float TANH_SCALE = 2.885390081777927f;  // 2*log2(e)

typedef __attribute__((ext_vector_type(8))) short bf16x8;
typedef __attribute__((ext_vector_type(4))) float f32x4;

__device__ __forceinline__ float fast_exp2(float x) { return __builtin_amdgcn_exp2f(x); }
__device__ __forceinline__ float fast_rcp(float x)  { return __builtin_amdgcn_rcpf(x); }

__device__ __forceinline__ unsigned int f2bf(float f) {
    unsigned int u = __float_as_uint(f);
    u += 0x7FFF + ((u >> 16) & 1);   // RNE
    return u >> 16;
}

__device__ __forceinline__ void async_copy16(const void* g, void* l) {
    __builtin_amdgcn_global_load_lds(
        (const __attribute__((address_space(1))) unsigned int*)g,
        (__attribute__((address_space(3))) unsigned int*)l, 16, 0, 0);
}

// f32 -> bf16 pre-convert: queries (131072), keys (2097152), W1 (524288) elems.
__global__ __launch_bounds__(256) void convert_bf16(
    const float* __restrict__ q, const float* __restrict__ k,
    const float* __restrict__ w, unsigned short* __restrict__ qb,
    unsigned short* __restrict__ kb, unsigned short* __restrict__ wb)
{
    int id = blockIdx.x * 256 + threadIdx.x;
    const float* src; unsigned short* dst; int off;
    if (id < 32768)        { src = q; dst = qb; off = id; }
    else if (id < 557056)  { src = k; dst = kb; off = id - 32768; }
    else                   { src = w; dst = wb; off = id - 557056; }
    float4 v = ((const float4*)src)[off];
    ushort4 o;
    o.x = (unsigned short)f2bf(v.x); o.y = (unsigned short)f2bf(v.y);
    o.z = (unsigned short)f2bf(v.z); o.w = (unsigned short)f2bf(v.w);
    ((ushort4*)dst)[off] = o;
}

// Fused q_proj/k_proj GEMM, bf16 MFMA, global_load_lds staging.
// C[m][n] = (sum_k A[m][k]*W1[n][col_off+k] + bias[n]) * TANH_SCALE
// blocks 0..511: k_proj; 512..543: q_proj. Tile 64x64, BK=64, 4 waves 2x2.
// LDS rows 128 B DMA-packed; XOR swizzle keeps ds_read_b128 <=2-way.
__global__ __launch_bounds__(256) void proj_mfma(
    const unsigned short* __restrict__ qb, const unsigned short* __restrict__ kb,
    const unsigned short* __restrict__ wb, const float* __restrict__ b1,
    float* __restrict__ qp, float* __restrict__ kp)
{
    __shared__ __align__(16) unsigned short As[64][64];
    __shared__ __align__(16) unsigned short Ws[64][64];

    const int bx = blockIdx.x;
    const unsigned short* A; float* C; const float* bias; int mb, nb, col_off;
    if (bx < 512) {
        A = kb; C = kp; bias = b1; col_off = 512;
        mb = (bx >> 3) * 64; nb = (bx & 7) * 64;
    } else {
        int b2 = bx - 512;
        A = qb; C = qp; bias = nullptr; col_off = 0;
        mb = (b2 >> 3) * 64; nb = (b2 & 7) * 64;
    }

    const int t = threadIdx.x;
    const int l = t & 63;
    const int wv = t >> 6;
    const int wm = (wv & 1) * 32;
    const int wn = (wv >> 1) * 32;
    const int lane16 = l & 15;
    const int quad   = l >> 4;
    const int r8   = l >> 3;
    const int schk = (l & 7) ^ r8;

    f32x4 acc[2][2] = {{{0.f,0.f,0.f,0.f},{0.f,0.f,0.f,0.f}},
                       {{0.f,0.f,0.f,0.f},{0.f,0.f,0.f,0.f}}};

    for (int kc = 0; kc < DIM; kc += 64) {
#pragma unroll
        for (int i = 0; i < 2; ++i) {
            int rbase = wv * 16 + i * 8;
            async_copy16(A + (size_t)(mb + rbase + r8) * DIM + kc + schk * 8, &As[rbase][0]);
            async_copy16(wb + (size_t)(nb + rbase + r8) * 1024 + col_off + kc + schk * 8, &Ws[rbase][0]);
        }
        __syncthreads();

#pragma unroll
        for (int ks = 0; ks < 2; ++ks) {
            int cc = ks * 4 + quad;
            int sw = (cc ^ (lane16 & 7)) << 3;
            bf16x8 a0  = *(const bf16x8*)&As[wm + lane16][sw];
            bf16x8 a1  = *(const bf16x8*)&As[wm + 16 + lane16][sw];
            bf16x8 b0  = *(const bf16x8*)&Ws[wn + lane16][sw];
            bf16x8 b1v = *(const bf16x8*)&Ws[wn + 16 + lane16][sw];
            acc[0][0] = __builtin_amdgcn_mfma_f32_16x16x32_bf16(a0, b0,  acc[0][0], 0, 0, 0);
            acc[0][1] = __builtin_amdgcn_mfma_f32_16x16x32_bf16(a0, b1v, acc[0][1], 0, 0, 0);
            acc[1][0] = __builtin_amdgcn_mfma_f32_16x16x32_bf16(a1, b0,  acc[1][0], 0, 0, 0);
            acc[1][1] = __builtin_amdgcn_mfma_f32_16x16x32_bf16(a1, b1v, acc[1][1], 0, 0, 0);
        }
        __syncthreads();
    }

#pragma unroll
    for (int mi = 0; mi < 2; ++mi) {
#pragma unroll
        for (int ni = 0; ni < 2; ++ni) {
            int col = nb + wn + 16 * ni + lane16;
            float bv = bias ? bias[col] : 0.0f;
#pragma unroll
            for (int r = 0; r < 4; ++r) {
                int row = mb + wm + 16 * mi + quad * 4 + r;
                C[(size_t)row * DIM + col] = (acc[mi][ni][r] + bv) * TANH_SCALE;
            }
        }
    }
}

// e[b,q,s] = exp2(-TANH_SCALE * t),  t = sum_h w2[h]*rcp(1+exp2(qp'+kp'))
// (qp',kp' pre-scaled by 2log2e; logits C-2t, C cancels after normalization;
//  |t|<=12 so unnormalized exp2 cannot overflow f32 — no max pass needed).
// Also accumulates row sums (atomic, ~32 adds/address).
// Tile 16q x 32s, full h. Grid (32 st, 4 qt, 4 b) = 512 blocks.
__global__ __launch_bounds__(256) void scores_kernel(
    const float* __restrict__ qp, const float* __restrict__ kp,
    const float* __restrict__ w2, float* __restrict__ sc,
    float* __restrict__ sums)
{
    __shared__ __align__(16) float qs[16][68];
    __shared__ __align__(16) float ks[32][68];
    __shared__ __align__(16) float ws2[512];
    const int t     = threadIdx.x;
    const int sb    = blockIdx.x * 32;
    const int qrow0 = blockIdx.z * 64 + blockIdx.y * 16;
    const int krow0 = blockIdx.z * 1024 + sb;

    if (t < 128) *(float4*)&ws2[t << 2] = *(const float4*)(w2 + (t << 2));

    const int tq = t >> 4;
    const int ts = t & 15;
    float acc0 = 0.f, acc1 = 0.f;

    for (int kc = 0; kc < DIM; kc += 64) {
        {
            int r = t >> 4, g = (t & 15) << 2;
            *(float4*)&qs[r][g] = *(const float4*)(qp + (size_t)(qrow0 + r) * DIM + kc + g);
        }
#pragma unroll
        for (int rr = 0; rr < 2; ++rr) {
            int idx = t + rr * 256;
            int r = idx >> 4, g = (idx & 15) << 2;
            *(float4*)&ks[r][g] = *(const float4*)(kp + (size_t)(krow0 + r) * DIM + kc + g);
        }
        __syncthreads();
#pragma unroll
        for (int k4 = 0; k4 < 16; ++k4) {
            float4 qv = *(const float4*)&qs[tq][k4 << 2];
            float4 k0 = *(const float4*)&ks[ts][k4 << 2];
            float4 k1 = *(const float4*)&ks[ts + 16][k4 << 2];
            float4 wv = *(const float4*)&ws2[kc + (k4 << 2)];
            acc0 = fmaf(wv.x, fast_rcp(1.0f + fast_exp2(qv.x + k0.x)), acc0);
            acc1 = fmaf(wv.x, fast_rcp(1.0f + fast_exp2(qv.x + k1.x)), acc1);
            acc0 = fmaf(wv.y, fast_rcp(1.0f + fast_exp2(qv.y + k0.y)), acc0);
            acc1 = fmaf(wv.y, fast_rcp(1.0f + fast_exp2(qv.y + k1.y)), acc1);
            acc0 = fmaf(wv.z, fast_rcp(1.0f + fast_exp2(qv.z + k0.z)), acc0);
            acc1 = fmaf(wv.z, fast_rcp(1.0f + fast_exp2(qv.z + k1.z)), acc1);
            acc0 = fmaf(wv.w, fast_rcp(1.0f + fast_exp2(qv.w + k0.w)), acc0);
            acc1 = fmaf(wv.w, fast_rcp(1.0f + fast_exp2(qv.w + k1.w)), acc1);
        }
        __syncthreads();
    }
    float e0 = fast_exp2(-TANH_SCALE * acc0);
    float e1 = fast_exp2(-TANH_SCALE * acc1);
    sc[(size_t)(qrow0 + tq) * SLEN + sb + ts]      = e0;
    sc[(size_t)(qrow0 + tq) * SLEN + sb + ts + 16] = e1;

    float rsum = e0 + e1;
#pragma unroll
    for (int m = 1; m < 16; m <<= 1) rsum += __shfl_xor(rsum, m, 64);
    if (ts == 0) atomicAdd(&sums[qrow0 + tq], rsum);
}

// pt[kt][b*64+q][v] = sum over 128-s chunk of e*values. Plain stores.
// Grid (8 vt, 8 kt, 4 b); tile 64q x 64v x 128s.
__global__ __launch_bounds__(256) void av_gemm(
    const float* __restrict__ e, const float* __restrict__ values,
    float* __restrict__ pt)
{
    __shared__ __align__(16) float As[32][68];
    __shared__ __align__(16) float Bs[32][68];
    const int t  = threadIdx.x;
    const int nb = blockIdx.x * 64;
    const int kt = blockIdx.y;
    const int kb = kt * 128;
    const int b  = blockIdx.z;
    const int tx = t & 15, ty = t >> 4;
    float acc[4][4] = {};
    for (int kc = 0; kc < 128; kc += 32) {
        const int k0 = kb + kc;
#pragma unroll
        for (int r = 0; r < 2; ++r) {
            int idx = t + r * 256;
            int m   = idx >> 3;
            int k4  = (idx & 7) << 2;
            float4 av = *(const float4*)(e + (size_t)(b * 64 + m) * SLEN + k0 + k4);
            As[k4 + 0][m] = av.x; As[k4 + 1][m] = av.y;
            As[k4 + 2][m] = av.z; As[k4 + 3][m] = av.w;
            int kk = idx >> 4;
            int g  = (idx & 15) << 2;
            *(float4*)&Bs[kk][g] =
                *(const float4*)(values + (size_t)(b * 1024 + k0 + kk) * DIM + nb + g);
        }
        __syncthreads();
#pragma unroll
        for (int k = 0; k < 32; ++k) {
            float4 a  = *(const float4*)&As[k][ty << 2];
            float4 bv = *(const float4*)&Bs[k][tx << 2];
            float am[4] = {a.x, a.y, a.z, a.w};
            float bn[4] = {bv.x, bv.y, bv.z, bv.w};
#pragma unroll
            for (int i = 0; i < 4; ++i)
#pragma unroll
                for (int j = 0; j < 4; ++j)
                    acc[i][j] = fmaf(am[i], bn[j], acc[i][j]);
        }
        __syncthreads();
    }
#pragma unroll
    for (int i = 0; i < 4; ++i) {
        int row = b * 64 + (ty << 2) + i;
        float4 o;
        o.x = acc[i][0]; o.y = acc[i][1]; o.z = acc[i][2]; o.w = acc[i][3];
        *(float4*)(pt + ((size_t)kt * 256 + row) * DIM + nb + (tx << 2)) = o;
    }
}

// out = (sum_{kt=0..7} pt[kt]) / sums[row]. 32768 float4s, grid 128 x 256.
__global__ __launch_bounds__(256) void reduce_kernel(
    const float* __restrict__ pt, const float* __restrict__ sums,
    float* __restrict__ out)
{
    int idx = blockIdx.x * 256 + threadIdx.x;
    const float4* p = (const float4*)pt;
    float4 a = p[idx];
#pragma unroll
    for (int k = 1; k < 8; ++k) {
        float4 v = p[k * 32768 + idx];
        a.x += v.x; a.y += v.y; a.z += v.z; a.w += v.w;
    }
    float r = fast_rcp(sums[idx >> 7]);   // row = idx*4/512
    a.x *= r; a.y *= r; a.z *= r; a.w *= r;
    ((float4*)out)[idx] = a;
}

extern "C" void kernel_launch(void* const* d_in, const int* in_sizes, int n_in,
                              void* d_out, int out_size, void* d_ws, size_t ws_size,
                              hipStream_t stream) {
    const float* queries = (const float*)d_in[0];
    const float* keys    = (const float*)d_in[1];
    const float* values  = (const float*)d_in[2];
    const float* W1      = (const float*)d_in[3];
    const float* b1      = (const float*)d_in[4];
    const float* w2      = (const float*)d_in[5];
    float* out = (float*)d_out;

    float* qp   = (float*)d_ws;                     // 256*512 f32
    float* kp   = qp + 256 * 512;                   // 4096*512 f32
    float* sc   = kp + 4096 * 512;                  // 256*1024 f32 (e values)
    float* pt   = sc + 256 * 1024;                  // 8 x 256*512 f32
    float* sums = pt + 8 * 256 * 512;               // 256 f32
    unsigned short* qbf = (unsigned short*)(sums + 256);
    unsigned short* kbf = qbf + 256 * 512;
    unsigned short* wbf = kbf + 4096 * 512;
    (void)in_sizes; (void)n_in; (void)ws_size; (void)out_size;

    hipMemsetAsync(sums, 0, 256 * sizeof(float), stream);
    convert_bf16<<<dim3(2688), 256, 0, stream>>>(queries, keys, W1, qbf, kbf, wbf);
    proj_mfma<<<dim3(544), 256, 0, stream>>>(qbf, kbf, wbf, b1, qp, kp);
    scores_kernel<<<dim3(32, 4, 4), 256, 0, stream>>>(qp, kp, w2, sc, sums);
    av_gemm<<<dim3(8, 8, 4), 256, 0, stream>>>(sc, values, pt);
    reduce_kernel<<<dim3(128), 256, 0, stream>>>(pt, sums, out);
}

// Round 7
// 126.534 us; speedup vs baseline: 1.0448x; 1.0448x over previous
//
#include <hip/hip_runtime.h>

// AdditiveAttention: b=4, n_q=64, s=1024, Q_DIM=K_DIM=HID=VDIM=512, f32 in/out.
// R7: revert cooperative mega-kernel (didn't execute under graph capture).
// R4 pipeline + h-split scores (proven 1024-block config, 4 acc chains) +
// combine kernel (e=exp2(-scale*(t0+t1)), normalize; no max pass needed since
// |t|<=12 -> no overflow). 6 launches, no atomics, no memsets.

static constexpr int SLEN = 1024;
static constexpr int DIM  = 512;
static constexpr float TANH_SCALE = 2.885390081777927f;  // 2*log2(e)

typedef __attribute__((ext_vector_type(8))) short bf16x8;
typedef __attribute__((ext_vector_type(4))) float f32x4;

__device__ __forceinline__ float fast_exp2(float x) { return __builtin_amdgcn_exp2f(x); }
__device__ __forceinline__ float fast_rcp(float x)  { return __builtin_amdgcn_rcpf(x); }

__device__ __forceinline__ unsigned int f2bf(float f) {
    unsigned int u = __float_as_uint(f);
    u += 0x7FFF + ((u >> 16) & 1);   // RNE
    return u >> 16;
}

__device__ __forceinline__ void async_copy16(const void* g, void* l) {
    __builtin_amdgcn_global_load_lds(
        (const __attribute__((address_space(1))) unsigned int*)g,
        (__attribute__((address_space(3))) unsigned int*)l, 16, 0, 0);
}

// f32 -> bf16 pre-convert: queries (131072), keys (2097152), W1 (524288) elems.
__global__ __launch_bounds__(256) void convert_bf16(
    const float* __restrict__ q, const float* __restrict__ k,
    const float* __restrict__ w, unsigned short* __restrict__ qb,
    unsigned short* __restrict__ kb, unsigned short* __restrict__ wb)
{
    int id = blockIdx.x * 256 + threadIdx.x;
    const float* src; unsigned short* dst; int off;
    if (id < 32768)        { src = q; dst = qb; off = id; }
    else if (id < 557056)  { src = k; dst = kb; off = id - 32768; }
    else                   { src = w; dst = wb; off = id - 557056; }
    float4 v = ((const float4*)src)[off];
    ushort4 o;
    o.x = (unsigned short)f2bf(v.x); o.y = (unsigned short)f2bf(v.y);
    o.z = (unsigned short)f2bf(v.z); o.w = (unsigned short)f2bf(v.w);
    ((ushort4*)dst)[off] = o;
}

// Fused q_proj/k_proj GEMM, bf16 MFMA, global_load_lds staging.
// C[m][n] = (sum_k A[m][k]*W1[n][col_off+k] + bias[n]) * TANH_SCALE
// blocks 0..511: k_proj; 512..543: q_proj. Tile 64x64, BK=64, 4 waves 2x2.
// LDS rows 128 B DMA-packed; XOR swizzle keeps ds_read_b128 <=2-way.
__global__ __launch_bounds__(256) void proj_mfma(
    const unsigned short* __restrict__ qb, const unsigned short* __restrict__ kb,
    const unsigned short* __restrict__ wb, const float* __restrict__ b1,
    float* __restrict__ qp, float* __restrict__ kp)
{
    __shared__ __align__(16) unsigned short As[64][64];
    __shared__ __align__(16) unsigned short Ws[64][64];

    const int bx = blockIdx.x;
    const unsigned short* A; float* C; const float* bias; int mb, nb, col_off;
    if (bx < 512) {
        A = kb; C = kp; bias = b1; col_off = 512;
        mb = (bx >> 3) * 64; nb = (bx & 7) * 64;
    } else {
        int b2 = bx - 512;
        A = qb; C = qp; bias = nullptr; col_off = 0;
        mb = (b2 >> 3) * 64; nb = (b2 & 7) * 64;
    }

    const int t = threadIdx.x;
    const int l = t & 63;
    const int wv = t >> 6;
    const int wm = (wv & 1) * 32;
    const int wn = (wv >> 1) * 32;
    const int lane16 = l & 15;
    const int quad   = l >> 4;
    const int r8   = l >> 3;
    const int schk = (l & 7) ^ r8;

    f32x4 acc[2][2] = {{{0.f,0.f,0.f,0.f},{0.f,0.f,0.f,0.f}},
                       {{0.f,0.f,0.f,0.f},{0.f,0.f,0.f,0.f}}};

    for (int kc = 0; kc < DIM; kc += 64) {
#pragma unroll
        for (int i = 0; i < 2; ++i) {
            int rbase = wv * 16 + i * 8;
            async_copy16(A + (size_t)(mb + rbase + r8) * DIM + kc + schk * 8, &As[rbase][0]);
            async_copy16(wb + (size_t)(nb + rbase + r8) * 1024 + col_off + kc + schk * 8, &Ws[rbase][0]);
        }
        __syncthreads();

#pragma unroll
        for (int ks = 0; ks < 2; ++ks) {
            int cc = ks * 4 + quad;
            int sw = (cc ^ (lane16 & 7)) << 3;
            bf16x8 a0  = *(const bf16x8*)&As[wm + lane16][sw];
            bf16x8 a1  = *(const bf16x8*)&As[wm + 16 + lane16][sw];
            bf16x8 b0  = *(const bf16x8*)&Ws[wn + lane16][sw];
            bf16x8 b1v = *(const bf16x8*)&Ws[wn + 16 + lane16][sw];
            acc[0][0] = __builtin_amdgcn_mfma_f32_16x16x32_bf16(a0, b0,  acc[0][0], 0, 0, 0);
            acc[0][1] = __builtin_amdgcn_mfma_f32_16x16x32_bf16(a0, b1v, acc[0][1], 0, 0, 0);
            acc[1][0] = __builtin_amdgcn_mfma_f32_16x16x32_bf16(a1, b0,  acc[1][0], 0, 0, 0);
            acc[1][1] = __builtin_amdgcn_mfma_f32_16x16x32_bf16(a1, b1v, acc[1][1], 0, 0, 0);
        }
        __syncthreads();
    }

#pragma unroll
    for (int mi = 0; mi < 2; ++mi) {
#pragma unroll
        for (int ni = 0; ni < 2; ++ni) {
            int col = nb + wn + 16 * ni + lane16;
            float bv = bias ? bias[col] : 0.0f;
#pragma unroll
            for (int r = 0; r < 4; ++r) {
                int row = mb + wm + 16 * mi + quad * 4 + r;
                C[(size_t)row * DIM + col] = (acc[mi][ni][r] + bv) * TANH_SCALE;
            }
        }
    }
}

// t_half[b,q,s] = sum_{h in half} w2[h]*rcp(1+exp2(qp'+kp'))  (qp',kp'
// pre-scaled by 2log2e). Tile 16q x 32s, 4 indep acc chains (2s x 2k-parity).
// Grid (32 st, 4qt x 2half, 4 b) = 1024 blocks -> 16 waves/CU for trans pipe.
__global__ __launch_bounds__(256) void scores_kernel(
    const float* __restrict__ qp, const float* __restrict__ kp,
    const float* __restrict__ w2, float* __restrict__ th)
{
    __shared__ __align__(16) float qs[16][68];
    __shared__ __align__(16) float ks[32][68];
    __shared__ __align__(16) float ws2[256];
    const int t     = threadIdx.x;
    const int sb    = blockIdx.x * 32;
    const int qt    = blockIdx.y & 3;
    const int half  = blockIdx.y >> 2;
    const int kbase = half * 256;
    const int qrow0 = blockIdx.z * 64 + qt * 16;
    const int krow0 = blockIdx.z * 1024 + sb;
    float* thh = th + (size_t)half * 256 * SLEN;

    if (t < 64) *(float4*)&ws2[t << 2] = *(const float4*)(w2 + kbase + (t << 2));

    const int tq = t >> 4;
    const int ts = t & 15;
    float a00 = 0.f, a01 = 0.f, a10 = 0.f, a11 = 0.f;

    for (int kc = 0; kc < 256; kc += 64) {
        {
            int r = t >> 4, g = (t & 15) << 2;
            *(float4*)&qs[r][g] = *(const float4*)(qp + (size_t)(qrow0 + r) * DIM + kbase + kc + g);
        }
#pragma unroll
        for (int rr = 0; rr < 2; ++rr) {
            int idx = t + rr * 256;
            int r = idx >> 4, g = (idx & 15) << 2;
            *(float4*)&ks[r][g] = *(const float4*)(kp + (size_t)(krow0 + r) * DIM + kbase + kc + g);
        }
        __syncthreads();
#pragma unroll
        for (int k4 = 0; k4 < 16; ++k4) {
            float4 qv = *(const float4*)&qs[tq][k4 << 2];
            float4 k0 = *(const float4*)&ks[ts][k4 << 2];
            float4 k1 = *(const float4*)&ks[ts + 16][k4 << 2];
            float4 wv = *(const float4*)&ws2[kc + (k4 << 2)];
            a00 = fmaf(wv.x, fast_rcp(1.0f + fast_exp2(qv.x + k0.x)), a00);
            a10 = fmaf(wv.x, fast_rcp(1.0f + fast_exp2(qv.x + k1.x)), a10);
            a01 = fmaf(wv.y, fast_rcp(1.0f + fast_exp2(qv.y + k0.y)), a01);
            a11 = fmaf(wv.y, fast_rcp(1.0f + fast_exp2(qv.y + k1.y)), a11);
            a00 = fmaf(wv.z, fast_rcp(1.0f + fast_exp2(qv.z + k0.z)), a00);
            a10 = fmaf(wv.z, fast_rcp(1.0f + fast_exp2(qv.z + k1.z)), a10);
            a01 = fmaf(wv.w, fast_rcp(1.0f + fast_exp2(qv.w + k0.w)), a01);
            a11 = fmaf(wv.w, fast_rcp(1.0f + fast_exp2(qv.w + k1.w)), a11);
        }
        __syncthreads();
    }
    thh[(size_t)(qrow0 + tq) * SLEN + sb + ts]      = a00 + a01;
    thh[(size_t)(qrow0 + tq) * SLEN + sb + ts + 16] = a10 + a11;
}

// combine: attn = e / sum(e), e = exp2(-TANH_SCALE*(t0+t1)). One block/row.
// No max pass: |t|<=12 so exp2 spans ~2^+-35, safe in f32; underflow harmless.
__global__ __launch_bounds__(256) void combine_kernel(
    const float* __restrict__ th, float* __restrict__ attn)
{
    const int row = blockIdx.x;
    const int t   = threadIdx.x;
    __shared__ float reds[4];
    size_t i0 = (size_t)row * SLEN + (t << 2);
    float4 a = *(const float4*)(th + i0);
    float4 b = *(const float4*)(th + 262144 + i0);
    float4 e;
    e.x = fast_exp2(-TANH_SCALE * (a.x + b.x));
    e.y = fast_exp2(-TANH_SCALE * (a.y + b.y));
    e.z = fast_exp2(-TANH_SCALE * (a.z + b.z));
    e.w = fast_exp2(-TANH_SCALE * (a.w + b.w));
    float s = e.x + e.y + e.z + e.w;
#pragma unroll
    for (int off = 32; off; off >>= 1) s += __shfl_xor(s, off, 64);
    if ((t & 63) == 0) reds[t >> 6] = s;
    __syncthreads();
    s = reds[0] + reds[1] + reds[2] + reds[3];
    float r = fast_rcp(s);
    e.x *= r; e.y *= r; e.z *= r; e.w *= r;
    *(float4*)(attn + i0) = e;
}

// pt[kt][b*64+q][v] = sum over 128-s chunk of attn*values. Plain stores.
// Grid (8 vt, 8 kt, 4 b); tile 64q x 64v x 128s.
__global__ __launch_bounds__(256) void av_gemm(
    const float* __restrict__ attn, const float* __restrict__ values,
    float* __restrict__ pt)
{
    __shared__ __align__(16) float As[32][68];
    __shared__ __align__(16) float Bs[32][68];
    const int t  = threadIdx.x;
    const int nb = blockIdx.x * 64;
    const int kt = blockIdx.y;
    const int kb = kt * 128;
    const int b  = blockIdx.z;
    const int tx = t & 15, ty = t >> 4;
    float acc[4][4] = {};
    for (int kc = 0; kc < 128; kc += 32) {
        const int k0 = kb + kc;
#pragma unroll
        for (int r = 0; r < 2; ++r) {
            int idx = t + r * 256;
            int m   = idx >> 3;
            int k4  = (idx & 7) << 2;
            float4 av = *(const float4*)(attn + (size_t)(b * 64 + m) * SLEN + k0 + k4);
            As[k4 + 0][m] = av.x; As[k4 + 1][m] = av.y;
            As[k4 + 2][m] = av.z; As[k4 + 3][m] = av.w;
            int kk = idx >> 4;
            int g  = (idx & 15) << 2;
            *(float4*)&Bs[kk][g] =
                *(const float4*)(values + (size_t)(b * 1024 + k0 + kk) * DIM + nb + g);
        }
        __syncthreads();
#pragma unroll
        for (int k = 0; k < 32; ++k) {
            float4 a  = *(const float4*)&As[k][ty << 2];
            float4 bv = *(const float4*)&Bs[k][tx << 2];
            float am[4] = {a.x, a.y, a.z, a.w};
            float bn[4] = {bv.x, bv.y, bv.z, bv.w};
#pragma unroll
            for (int i = 0; i < 4; ++i)
#pragma unroll
                for (int j = 0; j < 4; ++j)
                    acc[i][j] = fmaf(am[i], bn[j], acc[i][j]);
        }
        __syncthreads();
    }
#pragma unroll
    for (int i = 0; i < 4; ++i) {
        int row = b * 64 + (ty << 2) + i;
        float4 o;
        o.x = acc[i][0]; o.y = acc[i][1]; o.z = acc[i][2]; o.w = acc[i][3];
        *(float4*)(pt + ((size_t)kt * 256 + row) * DIM + nb + (tx << 2)) = o;
    }
}

// out = sum_{kt=0..7} pt[kt]. 32768 float4s, grid 128 x 256.
__global__ __launch_bounds__(256) void reduce_kernel(
    const float* __restrict__ pt, float* __restrict__ out)
{
    int idx = blockIdx.x * 256 + threadIdx.x;
    const float4* p = (const float4*)pt;
    float4 a = p[idx];
#pragma unroll
    for (int k = 1; k < 8; ++k) {
        float4 v = p[k * 32768 + idx];
        a.x += v.x; a.y += v.y; a.z += v.z; a.w += v.w;
    }
    ((float4*)out)[idx] = a;
}

extern "C" void kernel_launch(void* const* d_in, const int* in_sizes, int n_in,
                              void* d_out, int out_size, void* d_ws, size_t ws_size,
                              hipStream_t stream) {
    const float* queries = (const float*)d_in[0];
    const float* keys    = (const float*)d_in[1];
    const float* values  = (const float*)d_in[2];
    const float* W1      = (const float*)d_in[3];
    const float* b1      = (const float*)d_in[4];
    const float* w2      = (const float*)d_in[5];
    float* out = (float*)d_out;

    float* qp = (float*)d_ws;                       // 131072 f32
    float* kp = qp + 131072;                        // 2097152 f32
    float* th = kp + 2097152;                       // 2 x 262144 f32
    float* at = th + 2 * 262144;                    // 262144 f32
    float* pt = at + 262144;                        // 8 x 131072 f32
    unsigned short* qbf = (unsigned short*)(pt + 8 * 131072);
    unsigned short* kbf = qbf + 131072;
    unsigned short* wbf = kbf + 2097152;
    (void)in_sizes; (void)n_in; (void)ws_size; (void)out_size;

    convert_bf16<<<dim3(2688), 256, 0, stream>>>(queries, keys, W1, qbf, kbf, wbf);
    proj_mfma<<<dim3(544), 256, 0, stream>>>(qbf, kbf, wbf, b1, qp, kp);
    scores_kernel<<<dim3(32, 8, 4), 256, 0, stream>>>(qp, kp, w2, th);
    combine_kernel<<<dim3(256), 256, 0, stream>>>(th, at);
    av_gemm<<<dim3(8, 8, 4), 256, 0, stream>>>(at, values, pt);
    reduce_kernel<<<dim3(128), 256, 0, stream>>>(pt, out);
}